// Round 1
// baseline (302.311 us; speedup 1.0000x reference)
//
#include <hip/hip_runtime.h>
#include <hip/hip_bf16.h>

#define BB 8192
#define DD 256

typedef float f32x4 __attribute__((ext_vector_type(4)));
typedef __bf16 bf16x8 __attribute__((ext_vector_type(8)));

// log2(e) / 0.07
#define EXP2_SCALE 20.60992915555662f

// ---------------------------------------------------------------------------
// prep: one wave per row. Computes dist_sq (vs center), row norm, writes
// bf16 normalized features, accumulates sigma stats for normal rows.
// stats[0]=n_normal, [1]=masked_sum, [2]=sum_sq_normal
// ---------------------------------------------------------------------------
__global__ __launch_bounds__(256) void prep_kernel(
    const float* __restrict__ feat, const int* __restrict__ labels,
    const float* __restrict__ center, __hip_bfloat16* __restrict__ fn,
    float* __restrict__ dist_sq, float* __restrict__ stats)
{
    const int wave = threadIdx.x >> 6;
    const int lane = threadIdx.x & 63;
    const int row  = blockIdx.x * 4 + wave;

    const float4* frow = reinterpret_cast<const float4*>(feat + (size_t)row * DD);
    const float4* crow = reinterpret_cast<const float4*>(center);
    float4 x = frow[lane];
    float4 c = crow[lane];

    float d0 = x.x - c.x, d1 = x.y - c.y, d2 = x.z - c.z, d3 = x.w - c.w;
    float dsq = d0*d0 + d1*d1 + d2*d2 + d3*d3;
    float nsq = x.x*x.x + x.y*x.y + x.z*x.z + x.w*x.w;
    float sx  = x.x + x.y + x.z + x.w;

    #pragma unroll
    for (int m = 1; m < 64; m <<= 1) {
        dsq += __shfl_xor(dsq, m);
        nsq += __shfl_xor(nsq, m);
        sx  += __shfl_xor(sx,  m);
    }

    float rn = 1.0f / fmaxf(sqrtf(nsq), 1e-12f);

    ushort4 u;
    u.x = __builtin_bit_cast(unsigned short, __float2bfloat16(x.x * rn));
    u.y = __builtin_bit_cast(unsigned short, __float2bfloat16(x.y * rn));
    u.z = __builtin_bit_cast(unsigned short, __float2bfloat16(x.z * rn));
    u.w = __builtin_bit_cast(unsigned short, __float2bfloat16(x.w * rn));
    reinterpret_cast<ushort4*>(fn + (size_t)row * DD)[lane] = u;

    if (lane == 0) {
        dist_sq[row] = dsq;
        if (labels[row] == 0) {
            atomicAdd(&stats[0], 1.0f);
            atomicAdd(&stats[1], sx);
            atomicAdd(&stats[2], nsq);
        }
    }
}

// ---------------------------------------------------------------------------
// gram: fused Gram-matrix + masked exp row-sums.
// Grid: 512 blocks (32 row-blocks x 16 col-splits), 256 threads (4 waves).
// Each wave owns 64 rows (4 MFMA sub-tiles), holds all A-fragments (K=256)
// in registers, streams 16-col tiles over its 512-col slice.
// S_all[i] = sum_{j in slice, j!=i} exp(sim_ij)
// S_1[i]   = same but only label(j)==1 columns.
// ---------------------------------------------------------------------------
__global__ __launch_bounds__(256, 2) void gram_kernel(
    const __hip_bfloat16* __restrict__ fn, const int* __restrict__ labels,
    float* __restrict__ S_all, float* __restrict__ S_1)
{
    const int lane = threadIdx.x & 63;
    const int wave = threadIdx.x >> 6;
    const int l15  = lane & 15;
    const int quad = lane >> 4;

    const int cs = blockIdx.x & 15;   // col split
    const int rb = blockIdx.x >> 4;   // row block
    const int rowbase  = rb * 256 + wave * 64;
    const int colstart = cs * 512;
    const int kof = quad * 8;

    // A fragments: 4 sub-tiles (16 rows each) x 8 k-chunks of 32
    bf16x8 a[4][8];
    #pragma unroll
    for (int s = 0; s < 4; ++s) {
        const __hip_bfloat16* ap = fn + (size_t)(rowbase + s * 16 + l15) * DD + kof;
        #pragma unroll
        for (int kc = 0; kc < 8; ++kc)
            a[s][kc] = *reinterpret_cast<const bf16x8*>(ap + kc * 32);
    }

    float sall[4][4];
    float s1[4][4];
    #pragma unroll
    for (int s = 0; s < 4; ++s)
        #pragma unroll
        for (int r = 0; r < 4; ++r) { sall[s][r] = 0.0f; s1[s][r] = 0.0f; }

    for (int t = 0; t < 32; ++t) {
        const int colbase = colstart + t * 16;
        const int bcol = colbase + l15;

        const __hip_bfloat16* bp = fn + (size_t)bcol * DD + kof;
        bf16x8 b[8];
        #pragma unroll
        for (int kc = 0; kc < 8; ++kc)
            b[kc] = *reinterpret_cast<const bf16x8*>(bp + kc * 32);

        f32x4 acc[4] = { {0,0,0,0}, {0,0,0,0}, {0,0,0,0}, {0,0,0,0} };
        #pragma unroll
        for (int kc = 0; kc < 8; ++kc)
            #pragma unroll
            for (int s = 0; s < 4; ++s)
                acc[s] = __builtin_amdgcn_mfma_f32_16x16x32_bf16(a[s][kc], b[kc], acc[s], 0, 0, 0);

        const float w1 = (float)labels[bcol];

        if (colbase + 16 > rowbase && colbase < rowbase + 64) {
            // diagonal zone: exclude j==i cells
            #pragma unroll
            for (int s = 0; s < 4; ++s)
                #pragma unroll
                for (int r = 0; r < 4; ++r) {
                    const int grow = rowbase + s * 16 + quad * 4 + r;
                    float e = (grow == bcol) ? 0.0f : exp2f(acc[s][r] * EXP2_SCALE);
                    sall[s][r] += e;
                    s1[s][r] = fmaf(e, w1, s1[s][r]);
                }
        } else {
            #pragma unroll
            for (int s = 0; s < 4; ++s)
                #pragma unroll
                for (int r = 0; r < 4; ++r) {
                    float e = exp2f(acc[s][r] * EXP2_SCALE);
                    sall[s][r] += e;
                    s1[s][r] = fmaf(e, w1, s1[s][r]);
                }
        }
    }

    // reduce over the 16 columns held across lanes (low 4 lane bits), then
    // one atomic per row per block.
    #pragma unroll
    for (int s = 0; s < 4; ++s)
        #pragma unroll
        for (int r = 0; r < 4; ++r) {
            float va = sall[s][r];
            float v1 = s1[s][r];
            #pragma unroll
            for (int m = 1; m < 16; m <<= 1) {
                va += __shfl_xor(va, m);
                v1 += __shfl_xor(v1, m);
            }
            if (l15 == 0) {
                const int grow = rowbase + s * 16 + quad * 4 + r;
                atomicAdd(&S_all[grow], va);
                atomicAdd(&S_1[grow],  v1);
            }
        }
}

// ---------------------------------------------------------------------------
// finalize: per-row losses + mean reduction into out[0].
// ---------------------------------------------------------------------------
__global__ __launch_bounds__(256) void finalize_kernel(
    const int* __restrict__ labels, const float* __restrict__ dist_sq,
    const float* __restrict__ S_all, const float* __restrict__ S_1,
    const float* __restrict__ stats, const float* __restrict__ rsigma,
    float* __restrict__ out)
{
    const int i = blockIdx.x * 256 + threadIdx.x;

    // sigma / adaptive margin (same for all rows; recomputed per thread, cheap)
    const float n0   = stats[0];
    const float n_el = n0 * (float)DD;
    const float mean = stats[1] / n_el;
    const float var  = (stats[2] - n_el * mean * mean) / (n_el - 1.0f);
    const float sigma_new  = 0.9f * rsigma[0] + 0.1f * sqrtf(var);
    const float m_adaptive = 0.5f + 0.3f * sigma_new + 0.3f * (1.0f - 224.0f / 900.0f);

    const int l = labels[i];
    const float dsq = dist_sq[i];

    const float r_center = (l == 0) ? dsq : 0.0f;
    const float r_margin = (l == 1) ? fmaxf(m_adaptive - sqrtf(dsq), 0.0f) : 0.0f;

    const float sallv = S_all[i];
    const float s1v   = S_1[i];
    const float s0v   = sallv - s1v;
    const float pos = (l == 0) ? s0v : s1v;   // diag already excluded in gram
    const float neg = (l == 0) ? s1v : s0v;

    const float n1 = (float)BB - n0;
    const float cnt_same = ((l == 0) ? n0 : n1) - 1.0f;
    const float cnt_diff = (l == 0) ? n1 : n0;

    float r_con = 0.0f;
    if (cnt_same > 0.0f && cnt_diff > 0.0f)
        r_con = logf(pos + neg + 1e-8f) - logf(pos);

    float tot = (r_center + r_margin + 0.5f * r_con) * (1.0f / (float)BB);

    #pragma unroll
    for (int m = 1; m < 64; m <<= 1) tot += __shfl_xor(tot, m);
    if ((threadIdx.x & 63) == 0) atomicAdd(out, tot);
}

// ---------------------------------------------------------------------------
// launch
// ---------------------------------------------------------------------------
extern "C" void kernel_launch(void* const* d_in, const int* in_sizes, int n_in,
                              void* d_out, int out_size, void* d_ws, size_t ws_size,
                              hipStream_t stream) {
    const float* feat   = (const float*)d_in[0];
    const int*   labels = (const int*)d_in[1];
    const float* center = (const float*)d_in[2];
    const float* rsigma = (const float*)d_in[3];
    float* out = (float*)d_out;

    char* ws = (char*)d_ws;
    __hip_bfloat16* fn = (__hip_bfloat16*)ws;                     // B*D bf16 = 4 MB
    float* dist_sq = (float*)(ws + (size_t)BB * DD * 2);          // B floats
    float* S_all   = dist_sq + BB;                                // B floats
    float* S_1     = S_all + BB;                                  // B floats
    float* stats   = S_1 + BB;                                    // 8 floats

    // zero accumulators (ws and d_out are poisoned before every timed call)
    hipMemsetAsync(S_all, 0, (size_t)(2 * BB + 8) * sizeof(float), stream);
    hipMemsetAsync(out, 0, sizeof(float), stream);

    prep_kernel<<<dim3(BB / 4), dim3(256), 0, stream>>>(feat, labels, center, fn, dist_sq, stats);
    gram_kernel<<<dim3(32 * 16), dim3(256), 0, stream>>>(fn, labels, S_all, S_1);
    finalize_kernel<<<dim3(BB / 256), dim3(256), 0, stream>>>(labels, dist_sq, S_all, S_1, stats, rsigma, out);
}

// Round 2
// 151.416 us; speedup vs baseline: 1.9966x; 1.9966x over previous
//
#include <hip/hip_runtime.h>
#include <hip/hip_bf16.h>

#define BB 8192
#define DD 256

typedef float f32x4 __attribute__((ext_vector_type(4)));
typedef __bf16 bf16x8 __attribute__((ext_vector_type(8)));

// log2(e) / 0.07
#define EXP2_SCALE 20.60992915555662f

// ---------------------------------------------------------------------------
// prep: one wave per row. Computes dist_sq (vs center), row norm, writes
// bf16 normalized features + per-row sigma partials. NO global atomics.
// ---------------------------------------------------------------------------
__global__ __launch_bounds__(256) void prep_kernel(
    const float* __restrict__ feat, const int* __restrict__ labels,
    const float* __restrict__ center, __hip_bfloat16* __restrict__ fn,
    float* __restrict__ dist_sq, float* __restrict__ rowsum,
    float* __restrict__ rownsq)
{
    const int wave = threadIdx.x >> 6;
    const int lane = threadIdx.x & 63;
    const int row  = blockIdx.x * 4 + wave;

    const float4* frow = reinterpret_cast<const float4*>(feat + (size_t)row * DD);
    const float4* crow = reinterpret_cast<const float4*>(center);
    float4 x = frow[lane];
    float4 c = crow[lane];

    float d0 = x.x - c.x, d1 = x.y - c.y, d2 = x.z - c.z, d3 = x.w - c.w;
    float dsq = d0*d0 + d1*d1 + d2*d2 + d3*d3;
    float nsq = x.x*x.x + x.y*x.y + x.z*x.z + x.w*x.w;
    float sx  = x.x + x.y + x.z + x.w;

    #pragma unroll
    for (int m = 1; m < 64; m <<= 1) {
        dsq += __shfl_xor(dsq, m);
        nsq += __shfl_xor(nsq, m);
        sx  += __shfl_xor(sx,  m);
    }

    float rn = 1.0f / fmaxf(sqrtf(nsq), 1e-12f);

    ushort4 u;
    u.x = __builtin_bit_cast(unsigned short, __float2bfloat16(x.x * rn));
    u.y = __builtin_bit_cast(unsigned short, __float2bfloat16(x.y * rn));
    u.z = __builtin_bit_cast(unsigned short, __float2bfloat16(x.z * rn));
    u.w = __builtin_bit_cast(unsigned short, __float2bfloat16(x.w * rn));
    reinterpret_cast<ushort4*>(fn + (size_t)row * DD)[lane] = u;

    if (lane == 0) {
        const float m0 = (labels[row] == 0) ? 1.0f : 0.0f;
        dist_sq[row] = dsq;
        rowsum[row]  = sx  * m0;
        rownsq[row]  = nsq * m0;
    }
}

// ---------------------------------------------------------------------------
// reduce_stats: fold per-row partials into stats[0..2].
// stats[0]=n_normal, [1]=masked_sum, [2]=sum_sq_normal. 32 blocks => 96 atomics.
// ---------------------------------------------------------------------------
__global__ __launch_bounds__(256) void reduce_stats_kernel(
    const int* __restrict__ labels, const float* __restrict__ rowsum,
    const float* __restrict__ rownsq, float* __restrict__ stats)
{
    __shared__ float sh[3][4];
    const int i = blockIdx.x * 256 + threadIdx.x;
    const int lane = threadIdx.x & 63;
    const int wave = threadIdx.x >> 6;

    float cnt = (labels[i] == 0) ? 1.0f : 0.0f;
    float sx  = rowsum[i];
    float nsq = rownsq[i];

    #pragma unroll
    for (int m = 1; m < 64; m <<= 1) {
        cnt += __shfl_xor(cnt, m);
        sx  += __shfl_xor(sx,  m);
        nsq += __shfl_xor(nsq, m);
    }
    if (lane == 0) { sh[0][wave] = cnt; sh[1][wave] = sx; sh[2][wave] = nsq; }
    __syncthreads();
    if (threadIdx.x == 0) {
        atomicAdd(&stats[0], sh[0][0] + sh[0][1] + sh[0][2] + sh[0][3]);
        atomicAdd(&stats[1], sh[1][0] + sh[1][1] + sh[1][2] + sh[1][3]);
        atomicAdd(&stats[2], sh[2][0] + sh[2][1] + sh[2][2] + sh[2][3]);
    }
}

// ---------------------------------------------------------------------------
// gram: fused Gram-matrix + masked exp row-sums. (unchanged this round)
// Grid: 512 blocks (32 row-blocks x 16 col-splits), 256 threads (4 waves).
// ---------------------------------------------------------------------------
__global__ __launch_bounds__(256, 2) void gram_kernel(
    const __hip_bfloat16* __restrict__ fn, const int* __restrict__ labels,
    float* __restrict__ S_all, float* __restrict__ S_1)
{
    const int lane = threadIdx.x & 63;
    const int wave = threadIdx.x >> 6;
    const int l15  = lane & 15;
    const int quad = lane >> 4;

    const int cs = blockIdx.x & 15;   // col split
    const int rb = blockIdx.x >> 4;   // row block
    const int rowbase  = rb * 256 + wave * 64;
    const int colstart = cs * 512;
    const int kof = quad * 8;

    bf16x8 a[4][8];
    #pragma unroll
    for (int s = 0; s < 4; ++s) {
        const __hip_bfloat16* ap = fn + (size_t)(rowbase + s * 16 + l15) * DD + kof;
        #pragma unroll
        for (int kc = 0; kc < 8; ++kc)
            a[s][kc] = *reinterpret_cast<const bf16x8*>(ap + kc * 32);
    }

    float sall[4][4];
    float s1[4][4];
    #pragma unroll
    for (int s = 0; s < 4; ++s)
        #pragma unroll
        for (int r = 0; r < 4; ++r) { sall[s][r] = 0.0f; s1[s][r] = 0.0f; }

    for (int t = 0; t < 32; ++t) {
        const int colbase = colstart + t * 16;
        const int bcol = colbase + l15;

        const __hip_bfloat16* bp = fn + (size_t)bcol * DD + kof;
        bf16x8 b[8];
        #pragma unroll
        for (int kc = 0; kc < 8; ++kc)
            b[kc] = *reinterpret_cast<const bf16x8*>(bp + kc * 32);

        f32x4 acc[4] = { {0,0,0,0}, {0,0,0,0}, {0,0,0,0}, {0,0,0,0} };
        #pragma unroll
        for (int kc = 0; kc < 8; ++kc)
            #pragma unroll
            for (int s = 0; s < 4; ++s)
                acc[s] = __builtin_amdgcn_mfma_f32_16x16x32_bf16(a[s][kc], b[kc], acc[s], 0, 0, 0);

        const float w1 = (float)labels[bcol];

        if (colbase + 16 > rowbase && colbase < rowbase + 64) {
            #pragma unroll
            for (int s = 0; s < 4; ++s)
                #pragma unroll
                for (int r = 0; r < 4; ++r) {
                    const int grow = rowbase + s * 16 + quad * 4 + r;
                    float e = (grow == bcol) ? 0.0f : exp2f(acc[s][r] * EXP2_SCALE);
                    sall[s][r] += e;
                    s1[s][r] = fmaf(e, w1, s1[s][r]);
                }
        } else {
            #pragma unroll
            for (int s = 0; s < 4; ++s)
                #pragma unroll
                for (int r = 0; r < 4; ++r) {
                    float e = exp2f(acc[s][r] * EXP2_SCALE);
                    sall[s][r] += e;
                    s1[s][r] = fmaf(e, w1, s1[s][r]);
                }
        }
    }

    #pragma unroll
    for (int s = 0; s < 4; ++s)
        #pragma unroll
        for (int r = 0; r < 4; ++r) {
            float va = sall[s][r];
            float v1 = s1[s][r];
            #pragma unroll
            for (int m = 1; m < 16; m <<= 1) {
                va += __shfl_xor(va, m);
                v1 += __shfl_xor(v1, m);
            }
            if (l15 == 0) {
                const int grow = rowbase + s * 16 + quad * 4 + r;
                atomicAdd(&S_all[grow], va);
                atomicAdd(&S_1[grow],  v1);
            }
        }
}

// ---------------------------------------------------------------------------
// finalize: per-row losses + mean reduction into out[0].
// ---------------------------------------------------------------------------
__global__ __launch_bounds__(256) void finalize_kernel(
    const int* __restrict__ labels, const float* __restrict__ dist_sq,
    const float* __restrict__ S_all, const float* __restrict__ S_1,
    const float* __restrict__ stats, const float* __restrict__ rsigma,
    float* __restrict__ out)
{
    const int i = blockIdx.x * 256 + threadIdx.x;

    const float n0   = stats[0];
    const float n_el = n0 * (float)DD;
    const float mean = stats[1] / n_el;
    const float var  = (stats[2] - n_el * mean * mean) / (n_el - 1.0f);
    const float sigma_new  = 0.9f * rsigma[0] + 0.1f * sqrtf(var);
    const float m_adaptive = 0.5f + 0.3f * sigma_new + 0.3f * (1.0f - 224.0f / 900.0f);

    const int l = labels[i];
    const float dsq = dist_sq[i];

    const float r_center = (l == 0) ? dsq : 0.0f;
    const float r_margin = (l == 1) ? fmaxf(m_adaptive - sqrtf(dsq), 0.0f) : 0.0f;

    const float sallv = S_all[i];
    const float s1v   = S_1[i];
    const float s0v   = sallv - s1v;
    const float pos = (l == 0) ? s0v : s1v;
    const float neg = (l == 0) ? s1v : s0v;

    const float n1 = (float)BB - n0;
    const float cnt_same = ((l == 0) ? n0 : n1) - 1.0f;
    const float cnt_diff = (l == 0) ? n1 : n0;

    float r_con = 0.0f;
    if (cnt_same > 0.0f && cnt_diff > 0.0f)
        r_con = logf(pos + neg + 1e-8f) - logf(pos);

    float tot = (r_center + r_margin + 0.5f * r_con) * (1.0f / (float)BB);

    #pragma unroll
    for (int m = 1; m < 64; m <<= 1) tot += __shfl_xor(tot, m);
    if ((threadIdx.x & 63) == 0) atomicAdd(out, tot);
}

// ---------------------------------------------------------------------------
// launch
// ---------------------------------------------------------------------------
extern "C" void kernel_launch(void* const* d_in, const int* in_sizes, int n_in,
                              void* d_out, int out_size, void* d_ws, size_t ws_size,
                              hipStream_t stream) {
    const float* feat   = (const float*)d_in[0];
    const int*   labels = (const int*)d_in[1];
    const float* center = (const float*)d_in[2];
    const float* rsigma = (const float*)d_in[3];
    float* out = (float*)d_out;

    char* ws = (char*)d_ws;
    __hip_bfloat16* fn = (__hip_bfloat16*)ws;                     // B*D bf16 = 4 MB
    float* dist_sq = (float*)(ws + (size_t)BB * DD * 2);          // B floats
    float* S_all   = dist_sq + BB;                                // B floats
    float* S_1     = S_all + BB;                                  // B floats
    float* stats   = S_1 + BB;                                    // 8 floats
    float* rowsum  = stats + 8;                                   // B floats
    float* rownsq  = rowsum + BB;                                 // B floats

    // zero accumulators S_all, S_1, stats (contiguous)
    hipMemsetAsync(S_all, 0, (size_t)(2 * BB + 8) * sizeof(float), stream);
    hipMemsetAsync(out, 0, sizeof(float), stream);

    prep_kernel<<<dim3(BB / 4), dim3(256), 0, stream>>>(feat, labels, center, fn, dist_sq, rowsum, rownsq);
    reduce_stats_kernel<<<dim3(BB / 256), dim3(256), 0, stream>>>(labels, rowsum, rownsq, stats);
    gram_kernel<<<dim3(32 * 16), dim3(256), 0, stream>>>(fn, labels, S_all, S_1);
    finalize_kernel<<<dim3(BB / 256), dim3(256), 0, stream>>>(labels, dist_sq, S_all, S_1, stats, rsigma, out);
}

// Round 3
// 142.191 us; speedup vs baseline: 2.1261x; 1.0649x over previous
//
#include <hip/hip_runtime.h>
#include <hip/hip_bf16.h>

#define BB 8192
#define DD 256
#define ZN (2 * BB + 8)   // floats to zero: S_all, S_1, stats

typedef float f32x4 __attribute__((ext_vector_type(4)));
typedef __bf16 bf16x8 __attribute__((ext_vector_type(8)));

// sqrt(log2(e)/0.07): fn rows pre-scaled so MFMA acc = sim * log2(e)/T directly
#define FSCALE 4.53981600f

// ---------------------------------------------------------------------------
// prep: one wave per row. dist_sq vs center, sigma partials, and writes the
// normalized+scaled row in MFMA FRAGMENT ORDER:
//   cell(g,kc,quad,l15) = 16B holding elems [kc*32+quad*8, +8) of row g*16+l15
//   flat cell index = (g*8+kc)*64 + quad*16 + l15
// so gram's A/B fragment loads are F[base + lane] — perfectly coalesced.
// Also zeroes S_all/S_1/stats/out (replaces memset nodes).
// ---------------------------------------------------------------------------
__global__ __launch_bounds__(256) void prep_kernel(
    const float* __restrict__ feat, const int* __restrict__ labels,
    const float* __restrict__ center, __hip_bfloat16* __restrict__ fnf,
    float* __restrict__ dist_sq, float* __restrict__ rowsum,
    float* __restrict__ rownsq, float* __restrict__ zacc,
    float* __restrict__ out)
{
    const int gid = blockIdx.x * 256 + threadIdx.x;
    if (gid < ZN) zacc[gid] = 0.0f;
    if (gid == 0) out[0] = 0.0f;

    const int wave = threadIdx.x >> 6;
    const int lane = threadIdx.x & 63;
    const int row  = blockIdx.x * 4 + wave;

    const float4* frow = reinterpret_cast<const float4*>(feat + (size_t)row * DD);
    const float4* crow = reinterpret_cast<const float4*>(center);
    float4 x = frow[lane];
    float4 c = crow[lane];

    float d0 = x.x - c.x, d1 = x.y - c.y, d2 = x.z - c.z, d3 = x.w - c.w;
    float dsq = d0*d0 + d1*d1 + d2*d2 + d3*d3;
    float nsq = x.x*x.x + x.y*x.y + x.z*x.z + x.w*x.w;
    float sx  = x.x + x.y + x.z + x.w;

    #pragma unroll
    for (int m = 1; m < 64; m <<= 1) {
        dsq += __shfl_xor(dsq, m);
        nsq += __shfl_xor(nsq, m);
        sx  += __shfl_xor(sx,  m);
    }

    float rn = FSCALE / fmaxf(sqrtf(nsq), 1e-12f);

    ushort4 u;
    u.x = __builtin_bit_cast(unsigned short, __float2bfloat16(x.x * rn));
    u.y = __builtin_bit_cast(unsigned short, __float2bfloat16(x.y * rn));
    u.z = __builtin_bit_cast(unsigned short, __float2bfloat16(x.z * rn));
    u.w = __builtin_bit_cast(unsigned short, __float2bfloat16(x.w * rn));

    // lane holds elems e=4*lane..+3: kc=lane/8, quad=(lane%8)/2, half=lane&1
    const int g    = row >> 4;
    const int l15r = row & 15;
    const int kc   = lane >> 3;
    const int qd   = (lane & 7) >> 1;
    const int half = lane & 1;
    const size_t cell = (size_t)((g * 8 + kc) * 64 + qd * 16 + l15r);
    reinterpret_cast<ushort4*>(fnf)[cell * 2 + half] = u;

    if (lane == 0) {
        const float m0 = (labels[row] == 0) ? 1.0f : 0.0f;
        dist_sq[row] = dsq;
        rowsum[row]  = sx  * m0;
        rownsq[row]  = nsq * m0;
    }
}

// ---------------------------------------------------------------------------
// reduce_stats: fold per-row partials into stats[0..2]. 96 atomics total.
// ---------------------------------------------------------------------------
__global__ __launch_bounds__(256) void reduce_stats_kernel(
    const int* __restrict__ labels, const float* __restrict__ rowsum,
    const float* __restrict__ rownsq, float* __restrict__ stats)
{
    __shared__ float sh[3][4];
    const int i = blockIdx.x * 256 + threadIdx.x;
    const int lane = threadIdx.x & 63;
    const int wave = threadIdx.x >> 6;

    float cnt = (labels[i] == 0) ? 1.0f : 0.0f;
    float sx  = rowsum[i];
    float nsq = rownsq[i];

    #pragma unroll
    for (int m = 1; m < 64; m <<= 1) {
        cnt += __shfl_xor(cnt, m);
        sx  += __shfl_xor(sx,  m);
        nsq += __shfl_xor(nsq, m);
    }
    if (lane == 0) { sh[0][wave] = cnt; sh[1][wave] = sx; sh[2][wave] = nsq; }
    __syncthreads();
    if (threadIdx.x == 0) {
        atomicAdd(&stats[0], sh[0][0] + sh[0][1] + sh[0][2] + sh[0][3]);
        atomicAdd(&stats[1], sh[1][0] + sh[1][1] + sh[1][2] + sh[1][3]);
        atomicAdd(&stats[2], sh[2][0] + sh[2][1] + sh[2][2] + sh[2][3]);
    }
}

// ---------------------------------------------------------------------------
// gram: fused Gram + masked exp row-sums. fnf is in fragment order, so every
// load is F[base + lane] (1 KB coalesced). B double-buffered in registers.
// Grid: 512 blocks (32 row-blocks x 16 col-splits), 4 waves x 64 rows each.
// ---------------------------------------------------------------------------
__global__ __launch_bounds__(256, 2) void gram_kernel(
    const __hip_bfloat16* __restrict__ fnf, const int* __restrict__ labels,
    float* __restrict__ S_all, float* __restrict__ S_1)
{
    const int lane = threadIdx.x & 63;
    const int wave = threadIdx.x >> 6;
    const int l15  = lane & 15;
    const int quad = lane >> 4;

    const int cs = blockIdx.x & 15;   // col split
    const int rb = blockIdx.x >> 4;   // row block
    const int rowbase  = rb * 256 + wave * 64;
    const int colstart = cs * 512;

    const bf16x8* __restrict__ F = reinterpret_cast<const bf16x8*>(fnf);
    const int ga0 = rowbase >> 4;

    // A fragments: 4 sub-tiles x 8 k-chunks, coalesced loads
    bf16x8 a[4][8];
    #pragma unroll
    for (int s = 0; s < 4; ++s)
        #pragma unroll
        for (int kc = 0; kc < 8; ++kc)
            a[s][kc] = F[((ga0 + s) * 8 + kc) * 64 + lane];

    float sall[4][4];
    float sp1[4][4];
    #pragma unroll
    for (int s = 0; s < 4; ++s)
        #pragma unroll
        for (int r = 0; r < 4; ++r) { sall[s][r] = 0.0f; sp1[s][r] = 0.0f; }

    auto process = [&](int t, bf16x8 (&b)[8], float w1) {
        const int colbase = colstart + t * 16;
        f32x4 acc[4] = { {0,0,0,0}, {0,0,0,0}, {0,0,0,0}, {0,0,0,0} };
        #pragma unroll
        for (int kc = 0; kc < 8; ++kc)
            #pragma unroll
            for (int s = 0; s < 4; ++s)
                acc[s] = __builtin_amdgcn_mfma_f32_16x16x32_bf16(a[s][kc], b[kc], acc[s], 0, 0, 0);

        const int bcol = colbase + l15;
        if (colbase + 16 > rowbase && colbase < rowbase + 64) {
            #pragma unroll
            for (int s = 0; s < 4; ++s)
                #pragma unroll
                for (int r = 0; r < 4; ++r) {
                    const int grow = rowbase + s * 16 + quad * 4 + r;
                    float e = (grow == bcol) ? 0.0f : exp2f(acc[s][r]);
                    sall[s][r] += e;
                    sp1[s][r] = fmaf(e, w1, sp1[s][r]);
                }
        } else {
            #pragma unroll
            for (int s = 0; s < 4; ++s)
                #pragma unroll
                for (int r = 0; r < 4; ++r) {
                    float e = exp2f(acc[s][r]);
                    sall[s][r] += e;
                    sp1[s][r] = fmaf(e, w1, sp1[s][r]);
                }
        }
    };

    // B double buffer
    bf16x8 b0[8], b1[8];
    {
        const int gb = colstart >> 4;
        #pragma unroll
        for (int kc = 0; kc < 8; ++kc) b0[kc] = F[(gb * 8 + kc) * 64 + lane];
    }
    float w1a = (float)labels[colstart + l15];
    float w1b;

    for (int t = 0; t < 32; t += 2) {
        {   // prefetch t+1
            const int gb = (colstart + (t + 1) * 16) >> 4;
            #pragma unroll
            for (int kc = 0; kc < 8; ++kc) b1[kc] = F[(gb * 8 + kc) * 64 + lane];
            w1b = (float)labels[colstart + (t + 1) * 16 + l15];
        }
        process(t, b0, w1a);
        {   // prefetch t+2 (wraps harmlessly at the end)
            const int t2 = (t + 2) & 31;
            const int gb = (colstart + t2 * 16) >> 4;
            #pragma unroll
            for (int kc = 0; kc < 8; ++kc) b0[kc] = F[(gb * 8 + kc) * 64 + lane];
            w1a = (float)labels[colstart + t2 * 16 + l15];
        }
        process(t + 1, b1, w1b);
    }

    // reduce over the 16 cols held across low lane bits, one atomic/row/block
    #pragma unroll
    for (int s = 0; s < 4; ++s)
        #pragma unroll
        for (int r = 0; r < 4; ++r) {
            float va = sall[s][r];
            float v1 = sp1[s][r];
            #pragma unroll
            for (int m = 1; m < 16; m <<= 1) {
                va += __shfl_xor(va, m);
                v1 += __shfl_xor(v1, m);
            }
            if (l15 == 0) {
                const int grow = rowbase + s * 16 + quad * 4 + r;
                atomicAdd(&S_all[grow], va);
                atomicAdd(&S_1[grow],  v1);
            }
        }
}

// ---------------------------------------------------------------------------
// finalize: per-row losses + mean reduction into out[0].
// ---------------------------------------------------------------------------
__global__ __launch_bounds__(256) void finalize_kernel(
    const int* __restrict__ labels, const float* __restrict__ dist_sq,
    const float* __restrict__ S_all, const float* __restrict__ S_1,
    const float* __restrict__ stats, const float* __restrict__ rsigma,
    float* __restrict__ out)
{
    const int i = blockIdx.x * 256 + threadIdx.x;

    const float n0   = stats[0];
    const float n_el = n0 * (float)DD;
    const float mean = stats[1] / n_el;
    const float var  = (stats[2] - n_el * mean * mean) / (n_el - 1.0f);
    const float sigma_new  = 0.9f * rsigma[0] + 0.1f * sqrtf(var);
    const float m_adaptive = 0.5f + 0.3f * sigma_new + 0.3f * (1.0f - 224.0f / 900.0f);

    const int l = labels[i];
    const float dsq = dist_sq[i];

    const float r_center = (l == 0) ? dsq : 0.0f;
    const float r_margin = (l == 1) ? fmaxf(m_adaptive - sqrtf(dsq), 0.0f) : 0.0f;

    const float sallv = S_all[i];
    const float s1v   = S_1[i];
    const float s0v   = sallv - s1v;
    const float pos = (l == 0) ? s0v : s1v;
    const float neg = (l == 0) ? s1v : s0v;

    const float n1 = (float)BB - n0;
    const float cnt_same = ((l == 0) ? n0 : n1) - 1.0f;
    const float cnt_diff = (l == 0) ? n1 : n0;

    float r_con = 0.0f;
    if (cnt_same > 0.0f && cnt_diff > 0.0f)
        r_con = logf(pos + neg + 1e-8f) - logf(pos);

    float tot = (r_center + r_margin + 0.5f * r_con) * (1.0f / (float)BB);

    #pragma unroll
    for (int m = 1; m < 64; m <<= 1) tot += __shfl_xor(tot, m);
    if ((threadIdx.x & 63) == 0) atomicAdd(out, tot);
}

// ---------------------------------------------------------------------------
// launch
// ---------------------------------------------------------------------------
extern "C" void kernel_launch(void* const* d_in, const int* in_sizes, int n_in,
                              void* d_out, int out_size, void* d_ws, size_t ws_size,
                              hipStream_t stream) {
    const float* feat   = (const float*)d_in[0];
    const int*   labels = (const int*)d_in[1];
    const float* center = (const float*)d_in[2];
    const float* rsigma = (const float*)d_in[3];
    float* out = (float*)d_out;

    char* ws = (char*)d_ws;
    __hip_bfloat16* fnf = (__hip_bfloat16*)ws;                    // B*D bf16 = 4 MB, fragment order
    float* dist_sq = (float*)(ws + (size_t)BB * DD * 2);          // B floats
    float* S_all   = dist_sq + BB;                                // B floats
    float* S_1     = S_all + BB;                                  // B floats
    float* stats   = S_1 + BB;                                    // 8 floats
    float* rowsum  = stats + 8;                                   // B floats
    float* rownsq  = rowsum + BB;                                 // B floats

    prep_kernel<<<dim3(BB / 4), dim3(256), 0, stream>>>(feat, labels, center, fnf,
                                                        dist_sq, rowsum, rownsq, S_all, out);
    reduce_stats_kernel<<<dim3(BB / 256), dim3(256), 0, stream>>>(labels, rowsum, rownsq, stats);
    gram_kernel<<<dim3(32 * 16), dim3(256), 0, stream>>>(fnf, labels, S_all, S_1);
    finalize_kernel<<<dim3(BB / 256), dim3(256), 0, stream>>>(labels, dist_sq, S_all, S_1, stats, rsigma, out);
}

// Round 4
// 116.571 us; speedup vs baseline: 2.5934x; 1.2198x over previous
//
#include <hip/hip_runtime.h>
#include <hip/hip_bf16.h>

#define BB 8192
#define DD 256
#define ZN (2 * BB + 8)   // floats to zero: S_all, S_1, stats

typedef float f32x4 __attribute__((ext_vector_type(4)));
typedef __bf16 bf16x8 __attribute__((ext_vector_type(8)));

// sqrt(log2(e)/0.07): fn rows pre-scaled so MFMA acc = sim * log2(e)/T directly
#define FSCALE 4.53981600f

__device__ __forceinline__ void load16_to_lds(const void* g, void* l) {
    __builtin_amdgcn_global_load_lds(
        (const __attribute__((address_space(1))) unsigned int*)g,
        (__attribute__((address_space(3))) unsigned int*)l,
        16, 0, 0);
}

// ---------------------------------------------------------------------------
// prep: one wave per row. dist_sq vs center, sigma partials, writes the
// normalized+scaled row in MFMA FRAGMENT ORDER:
//   flat cell (16B) index = (g*8+kc)*64 + quad*16 + l15,  row = g*16+l15,
//   elems [kc*32+quad*8, +8). Also zeroes S_all/S_1/stats/out.
// ---------------------------------------------------------------------------
__global__ __launch_bounds__(256) void prep_kernel(
    const float* __restrict__ feat, const int* __restrict__ labels,
    const float* __restrict__ center, __hip_bfloat16* __restrict__ fnf,
    float* __restrict__ dist_sq, float* __restrict__ rowsum,
    float* __restrict__ rownsq, float* __restrict__ zacc,
    float* __restrict__ out)
{
    const int gid = blockIdx.x * 256 + threadIdx.x;
    if (gid < ZN) zacc[gid] = 0.0f;
    if (gid == 0) out[0] = 0.0f;

    const int wave = threadIdx.x >> 6;
    const int lane = threadIdx.x & 63;
    const int row  = blockIdx.x * 4 + wave;

    const float4* frow = reinterpret_cast<const float4*>(feat + (size_t)row * DD);
    const float4* crow = reinterpret_cast<const float4*>(center);
    float4 x = frow[lane];
    float4 c = crow[lane];

    float d0 = x.x - c.x, d1 = x.y - c.y, d2 = x.z - c.z, d3 = x.w - c.w;
    float dsq = d0*d0 + d1*d1 + d2*d2 + d3*d3;
    float nsq = x.x*x.x + x.y*x.y + x.z*x.z + x.w*x.w;
    float sx  = x.x + x.y + x.z + x.w;

    #pragma unroll
    for (int m = 1; m < 64; m <<= 1) {
        dsq += __shfl_xor(dsq, m);
        nsq += __shfl_xor(nsq, m);
        sx  += __shfl_xor(sx,  m);
    }

    float rn = FSCALE / fmaxf(sqrtf(nsq), 1e-12f);

    ushort4 u;
    u.x = __builtin_bit_cast(unsigned short, __float2bfloat16(x.x * rn));
    u.y = __builtin_bit_cast(unsigned short, __float2bfloat16(x.y * rn));
    u.z = __builtin_bit_cast(unsigned short, __float2bfloat16(x.z * rn));
    u.w = __builtin_bit_cast(unsigned short, __float2bfloat16(x.w * rn));

    // lane holds elems e=4*lane..+3: kc=lane/8, quad=(lane%8)/2, half=lane&1
    const int g    = row >> 4;
    const int l15r = row & 15;
    const int kc   = lane >> 3;
    const int qd   = (lane & 7) >> 1;
    const int half = lane & 1;
    const size_t cell = (size_t)((g * 8 + kc) * 64 + qd * 16 + l15r);
    reinterpret_cast<ushort4*>(fnf)[cell * 2 + half] = u;

    if (lane == 0) {
        const float m0 = (labels[row] == 0) ? 1.0f : 0.0f;
        dist_sq[row] = dsq;
        rowsum[row]  = sx  * m0;
        rownsq[row]  = nsq * m0;
    }
}

// ---------------------------------------------------------------------------
// reduce_stats: fold per-row partials into stats[0..2]. 96 atomics total.
// ---------------------------------------------------------------------------
__global__ __launch_bounds__(256) void reduce_stats_kernel(
    const int* __restrict__ labels, const float* __restrict__ rowsum,
    const float* __restrict__ rownsq, float* __restrict__ stats)
{
    __shared__ float sh[3][4];
    const int i = blockIdx.x * 256 + threadIdx.x;
    const int lane = threadIdx.x & 63;
    const int wave = threadIdx.x >> 6;

    float cnt = (labels[i] == 0) ? 1.0f : 0.0f;
    float sx  = rowsum[i];
    float nsq = rownsq[i];

    #pragma unroll
    for (int m = 1; m < 64; m <<= 1) {
        cnt += __shfl_xor(cnt, m);
        sx  += __shfl_xor(sx,  m);
        nsq += __shfl_xor(nsq, m);
    }
    if (lane == 0) { sh[0][wave] = cnt; sh[1][wave] = sx; sh[2][wave] = nsq; }
    __syncthreads();
    if (threadIdx.x == 0) {
        atomicAdd(&stats[0], sh[0][0] + sh[0][1] + sh[0][2] + sh[0][3]);
        atomicAdd(&stats[1], sh[1][0] + sh[1][1] + sh[1][2] + sh[1][3]);
        atomicAdd(&stats[2], sh[2][0] + sh[2][1] + sh[2][2] + sh[2][3]);
    }
}

// ---------------------------------------------------------------------------
// gram: fused Gram + masked exp row-sums.
// Per wave: 32 rows in registers (a[2][8] = 64 VGPRs, no spill).
// B tiles (16 cols = 8 KB, fragment order => contiguous) staged to LDS with
// async global_load_lds width=16, double-buffered; shared by all 4 waves.
// Grid: 1024 blocks = 64 row-blocks (128 rows) x 16 col-splits (512 cols).
// ---------------------------------------------------------------------------
__global__ __launch_bounds__(256, 4) void gram_kernel(
    const __hip_bfloat16* __restrict__ fnf, const int* __restrict__ labels,
    float* __restrict__ S_all, float* __restrict__ S_1)
{
    __shared__ __align__(16) char lds[2][8192];

    const int tid  = threadIdx.x;
    const int lane = tid & 63;
    const int wave = tid >> 6;
    const int l15  = lane & 15;
    const int quad = lane >> 4;

    const int cs = blockIdx.x & 15;       // col split
    const int rb = blockIdx.x >> 4;       // row block
    const int rowbase  = rb * 128 + wave * 32;
    const int colstart = cs * 512;

    const bf16x8* __restrict__ F = reinterpret_cast<const bf16x8*>(fnf);

    // A fragments: 2 sub-tiles x 8 k-chunks, coalesced loads
    bf16x8 a[2][8];
    #pragma unroll
    for (int s = 0; s < 2; ++s)
        #pragma unroll
        for (int kc = 0; kc < 8; ++kc)
            a[s][kc] = F[(size_t)(((rowbase >> 4) + s) * 8 + kc) * 64 + lane];

    float sall[2][4], sp1[2][4];
    #pragma unroll
    for (int s = 0; s < 2; ++s)
        #pragma unroll
        for (int r = 0; r < 4; ++r) { sall[s][r] = 0.0f; sp1[s][r] = 0.0f; }

    // stage tile t into buffer b (8 KB, two 4 KB chunks per block)
    auto stage = [&](int t, int b) {
        const char* gsrc = (const char*)fnf +
            (size_t)((colstart + t * 16) >> 4) * 8192 + (size_t)tid * 16;
        load16_to_lds(gsrc,        &lds[b][wave * 1024]);
        load16_to_lds(gsrc + 4096, &lds[b][4096 + wave * 1024]);
    };

    stage(0, 0);

    for (int t = 0; t < 32; ++t) {
        __syncthreads();                 // drains vmcnt: stage(t) landed
        if (t + 1 < 32) stage(t + 1, (t + 1) & 1);

        const bf16x8* Bt = reinterpret_cast<const bf16x8*>(lds[t & 1]);
        f32x4 acc0 = {0,0,0,0}, acc1 = {0,0,0,0};
        #pragma unroll
        for (int kc = 0; kc < 8; ++kc) {
            bf16x8 b = Bt[kc * 64 + lane];
            acc0 = __builtin_amdgcn_mfma_f32_16x16x32_bf16(a[0][kc], b, acc0, 0, 0, 0);
            acc1 = __builtin_amdgcn_mfma_f32_16x16x32_bf16(a[1][kc], b, acc1, 0, 0, 0);
        }

        const int colbase = colstart + t * 16;
        const int bcol = colbase + l15;
        const float w1 = (float)labels[bcol];

        if (colbase + 16 > rowbase && colbase < rowbase + 32) {
            #pragma unroll
            for (int r = 0; r < 4; ++r) {
                const int row0 = rowbase + quad * 4 + r;
                float e0 = (row0 == bcol) ? 0.0f : exp2f(acc0[r]);
                float e1 = (row0 + 16 == bcol) ? 0.0f : exp2f(acc1[r]);
                sall[0][r] += e0; sp1[0][r] = fmaf(e0, w1, sp1[0][r]);
                sall[1][r] += e1; sp1[1][r] = fmaf(e1, w1, sp1[1][r]);
            }
        } else {
            #pragma unroll
            for (int r = 0; r < 4; ++r) {
                float e0 = exp2f(acc0[r]);
                float e1 = exp2f(acc1[r]);
                sall[0][r] += e0; sp1[0][r] = fmaf(e0, w1, sp1[0][r]);
                sall[1][r] += e1; sp1[1][r] = fmaf(e1, w1, sp1[1][r]);
            }
        }
    }

    // reduce over the 16 cols held across low lane bits, one atomic/row/block
    #pragma unroll
    for (int s = 0; s < 2; ++s)
        #pragma unroll
        for (int r = 0; r < 4; ++r) {
            float va = sall[s][r];
            float v1 = sp1[s][r];
            #pragma unroll
            for (int m = 1; m < 16; m <<= 1) {
                va += __shfl_xor(va, m);
                v1 += __shfl_xor(v1, m);
            }
            if (l15 == 0) {
                const int grow = rowbase + s * 16 + quad * 4 + r;
                atomicAdd(&S_all[grow], va);
                atomicAdd(&S_1[grow],  v1);
            }
        }
}

// ---------------------------------------------------------------------------
// finalize: per-row losses + mean reduction into out[0].
// ---------------------------------------------------------------------------
__global__ __launch_bounds__(256) void finalize_kernel(
    const int* __restrict__ labels, const float* __restrict__ dist_sq,
    const float* __restrict__ S_all, const float* __restrict__ S_1,
    const float* __restrict__ stats, const float* __restrict__ rsigma,
    float* __restrict__ out)
{
    const int i = blockIdx.x * 256 + threadIdx.x;

    const float n0   = stats[0];
    const float n_el = n0 * (float)DD;
    const float mean = stats[1] / n_el;
    const float var  = (stats[2] - n_el * mean * mean) / (n_el - 1.0f);
    const float sigma_new  = 0.9f * rsigma[0] + 0.1f * sqrtf(var);
    const float m_adaptive = 0.5f + 0.3f * sigma_new + 0.3f * (1.0f - 224.0f / 900.0f);

    const int l = labels[i];
    const float dsq = dist_sq[i];

    const float r_center = (l == 0) ? dsq : 0.0f;
    const float r_margin = (l == 1) ? fmaxf(m_adaptive - sqrtf(dsq), 0.0f) : 0.0f;

    const float sallv = S_all[i];
    const float s1v   = S_1[i];
    const float s0v   = sallv - s1v;
    const float pos = (l == 0) ? s0v : s1v;
    const float neg = (l == 0) ? s1v : s0v;

    const float n1 = (float)BB - n0;
    const float cnt_same = ((l == 0) ? n0 : n1) - 1.0f;
    const float cnt_diff = (l == 0) ? n1 : n0;

    float r_con = 0.0f;
    if (cnt_same > 0.0f && cnt_diff > 0.0f)
        r_con = logf(pos + neg + 1e-8f) - logf(pos);

    float tot = (r_center + r_margin + 0.5f * r_con) * (1.0f / (float)BB);

    #pragma unroll
    for (int m = 1; m < 64; m <<= 1) tot += __shfl_xor(tot, m);
    if ((threadIdx.x & 63) == 0) atomicAdd(out, tot);
}

// ---------------------------------------------------------------------------
// launch
// ---------------------------------------------------------------------------
extern "C" void kernel_launch(void* const* d_in, const int* in_sizes, int n_in,
                              void* d_out, int out_size, void* d_ws, size_t ws_size,
                              hipStream_t stream) {
    const float* feat   = (const float*)d_in[0];
    const int*   labels = (const int*)d_in[1];
    const float* center = (const float*)d_in[2];
    const float* rsigma = (const float*)d_in[3];
    float* out = (float*)d_out;

    char* ws = (char*)d_ws;
    __hip_bfloat16* fnf = (__hip_bfloat16*)ws;                    // B*D bf16 = 4 MB, fragment order
    float* dist_sq = (float*)(ws + (size_t)BB * DD * 2);          // B floats
    float* S_all   = dist_sq + BB;                                // B floats
    float* S_1     = S_all + BB;                                  // B floats
    float* stats   = S_1 + BB;                                    // 8 floats
    float* rowsum  = stats + 8;                                   // B floats
    float* rownsq  = rowsum + BB;                                 // B floats

    prep_kernel<<<dim3(BB / 4), dim3(256), 0, stream>>>(feat, labels, center, fnf,
                                                        dist_sq, rowsum, rownsq, S_all, out);
    reduce_stats_kernel<<<dim3(BB / 256), dim3(256), 0, stream>>>(labels, rowsum, rownsq, stats);
    gram_kernel<<<dim3(64 * 16), dim3(256), 0, stream>>>(fnf, labels, S_all, S_1);
    finalize_kernel<<<dim3(BB / 256), dim3(256), 0, stream>>>(labels, dist_sq, S_all, S_1, stats, rsigma, out);
}